// Round 1
// baseline (1124.462 us; speedup 1.0000x reference)
//
#include <hip/hip_runtime.h>

typedef unsigned short u16;
typedef __attribute__((ext_vector_type(8))) short short8;
typedef __attribute__((ext_vector_type(4))) float f32x4;

#define AS1 __attribute__((address_space(1)))
#define AS3 __attribute__((address_space(3)))

__device__ __forceinline__ void async_cp16(const void* g, void* l) {
  __builtin_amdgcn_global_load_lds((const AS1 unsigned int*)g, (AS3 unsigned int*)l, 16, 0, 0);
}

__device__ __forceinline__ u16 f2bf(float f) {
  union { float f; unsigned u; } v; v.f = f;
  unsigned r = v.u + 0x7fffu + ((v.u >> 16) & 1u);
  return (u16)(r >> 16);
}
__device__ __forceinline__ float bf2f(u16 h) {
  union { unsigned u; float f; } v; v.u = ((unsigned)h) << 16;
  return v.f;
}

// ---------------------------------------------------------------------------
// GEMM: C[M,N] = A[M,K] @ B^T[N,K]^T, bf16 inputs, fp32 accumulate.
// MODE 0: Cf[m,n] += acc (f32, ldc=N)           -- tall delta GEMMs into residual
// MODE 1: bf16 row-major into Crow (packed [Xa|Xf] layout) + bf16 transposed into Ct
// MODE 2: bf16 row-major into Crow only
// Block 256 = 4 waves (2x2), tile 128x128, BK=32, 16x16x32 bf16 MFMA.
// ---------------------------------------------------------------------------
template<int MODE>
__global__ __launch_bounds__(256) void gemm_bt(
    const u16* __restrict__ A, const u16* __restrict__ B,
    int M, int N, int K,
    float* __restrict__ Cf,
    u16* __restrict__ Crow, int crow_ld, int crow_coloff,
    u16* __restrict__ Ct, int ct_ld)
{
  extern __shared__ char smem[];
  u16* sA = (u16*)smem;            // [128][32] bf16, row-major, no pad (global_load_lds layout)
  u16* sB = (u16*)(smem + 8192);   // [128][32]
  const int tid  = threadIdx.x;
  const int lane = tid & 63;
  const int wid  = tid >> 6;
  const int m0 = blockIdx.y * 128;
  const int n0 = blockIdx.x * 128;
  const int wm = (wid >> 1) * 64;
  const int wn = (wid & 1) * 64;
  const int ml = lane & 15;
  const int qd = lane >> 4;

  f32x4 acc[4][4];
  const f32x4 zero = {0.f, 0.f, 0.f, 0.f};
#pragma unroll
  for (int i = 0; i < 4; i++)
#pragma unroll
    for (int j = 0; j < 4; j++) acc[i][j] = zero;

  // staging: thread t loads 16B at global row (t>>2), k-chunk (t&3)*8 -> LDS byte t*16
  const int r4 = tid >> 2;
  const int c4 = (tid & 3) * 8;
  const u16* gA0 = A + (size_t)(m0 + r4) * K + c4;
  const u16* gA1 = A + (size_t)(m0 + 64 + r4) * K + c4;
  const u16* gB0 = B + (size_t)(n0 + r4) * K + c4;
  const u16* gB1 = B + (size_t)(n0 + 64 + r4) * K + c4;
  u16* lA0 = sA + wid * 512;          // wave-uniform base; HW adds lane*16B
  u16* lA1 = sA + 2048 + wid * 512;
  u16* lB0 = sB + wid * 512;
  u16* lB1 = sB + 2048 + wid * 512;

  for (int k0 = 0; k0 < K; k0 += 32) {
    async_cp16(gA0 + k0, lA0);
    async_cp16(gA1 + k0, lA1);
    async_cp16(gB0 + k0, lB0);
    async_cp16(gB1 + k0, lB1);
    __syncthreads();   // drains vmcnt -> LDS tiles ready
    short8 af[4], bfr[4];
#pragma unroll
    for (int i = 0; i < 4; i++)
      af[i] = *(const short8*)(sA + (wm + i * 16 + ml) * 32 + qd * 8);
#pragma unroll
    for (int j = 0; j < 4; j++)
      bfr[j] = *(const short8*)(sB + (wn + j * 16 + ml) * 32 + qd * 8);
#pragma unroll
    for (int i = 0; i < 4; i++)
#pragma unroll
      for (int j = 0; j < 4; j++)
        acc[i][j] = __builtin_amdgcn_mfma_f32_16x16x32_bf16(af[i], bfr[j], acc[i][j], 0, 0, 0);
    __syncthreads();   // protect LDS from next iter's staging
  }

  if constexpr (MODE == 0) {
#pragma unroll
    for (int i = 0; i < 4; i++) {
      const int mr = m0 + wm + i * 16 + qd * 4;
#pragma unroll
      for (int j = 0; j < 4; j++) {
        const int nc = n0 + wn + j * 16 + ml;
        float* p = Cf + (size_t)mr * N + nc;
#pragma unroll
        for (int r = 0; r < 4; r++) p[(size_t)r * N] += acc[i][j][r];
      }
    }
  } else {
    u16* T = (u16*)smem;  // [128][136] bf16 bounce buffer (aliases sA/sB; loop ended with barrier)
    // phase 1: row-major bf16 into packed Crow: row = m*(N/128)+(n0/128), col = n%128 + coloff
#pragma unroll
    for (int i = 0; i < 4; i++)
#pragma unroll
      for (int j = 0; j < 4; j++)
#pragma unroll
        for (int r = 0; r < 4; r++)
          T[(wm + i * 16 + qd * 4 + r) * 136 + wn + j * 16 + ml] = f2bf(acc[i][j][r]);
    __syncthreads();
    {
      const int row = tid >> 1, half = tid & 1;
      const size_t crow = (size_t)(m0 + row) * (N >> 7) + (n0 >> 7);
      u16* dst = Crow + crow * (size_t)crow_ld + crow_coloff + half * 64;
      const u16* src = T + row * 136 + half * 64;
#pragma unroll
      for (int u = 0; u < 8; u++) ((float4*)dst)[u] = ((const float4*)src)[u];
    }
    if constexpr (MODE == 1) {
      __syncthreads();
      // phase 2: transposed bf16: Ct[n][m]
#pragma unroll
      for (int i = 0; i < 4; i++)
#pragma unroll
        for (int j = 0; j < 4; j++)
#pragma unroll
          for (int r = 0; r < 4; r++)
            T[(wn + j * 16 + ml) * 136 + wm + i * 16 + qd * 4 + r] = f2bf(acc[i][j][r]);
      __syncthreads();
      const int row = tid >> 1, half = tid & 1;
      u16* dst = Ct + (size_t)(n0 + row) * ct_ld + m0 + half * 64;
      const u16* src = T + row * 136 + half * 64;
#pragma unroll
      for (int u = 0; u < 8; u++) ((float4*)dst)[u] = ((const float4*)src)[u];
    }
  }
}

// ---------------------------------------------------------------------------
// small kernels
// ---------------------------------------------------------------------------
__global__ void rowsum_k(const float* __restrict__ prior, float* __restrict__ rs) {
  const int i = blockIdx.x, t = threadIdx.x;
  const float* p = prior + (size_t)i * 2048;
  float s = 0.f;
  for (int j = t; j < 2048; j += 256) s += p[j];
  __shared__ float red[256];
  red[t] = s; __syncthreads();
  for (int o = 128; o; o >>= 1) { if (t < o) red[t] += red[t + o]; __syncthreads(); }
  if (t == 0) rs[i] = red[0];
}

__global__ void convprior_k(const float4* __restrict__ prior, const float* __restrict__ rs,
                            ushort4* __restrict__ dst) {
  const int idx = blockIdx.x * 256 + threadIdx.x;   // < 2048*2048/4
  const float inv = 1.0f / rs[idx >> 9];
  const float4 v = prior[idx];
  ushort4 o;
  o.x = f2bf(v.x * inv); o.y = f2bf(v.y * inv); o.z = f2bf(v.z * inv); o.w = f2bf(v.w * inv);
  dst[idx] = o;
}

// x (2048 x 8192 f32) -> Xt (8192 x 2048 bf16), tiled 64x64 transpose
__global__ void convx_k(const float* __restrict__ x, u16* __restrict__ xt) {
  __shared__ float S[64][65];
  const int t = threadIdx.x;
  const int j0 = blockIdx.y * 64;
  const int n0 = blockIdx.x * 64;
  const int rr = t >> 4, cc = (t & 15) * 4;
#pragma unroll
  for (int p = 0; p < 4; p++) {
    const float4 v = *(const float4*)(x + (size_t)(j0 + rr + p * 16) * 8192 + n0 + cc);
    S[rr + p * 16][cc + 0] = v.x; S[rr + p * 16][cc + 1] = v.y;
    S[rr + p * 16][cc + 2] = v.z; S[rr + p * 16][cc + 3] = v.w;
  }
  __syncthreads();
  const int nl = t >> 2, ch = (t & 3) * 16;
  alignas(16) u16 tmp[16];
#pragma unroll
  for (int u = 0; u < 16; u++) tmp[u] = f2bf(S[ch + u][nl]);
  float4* dst = (float4*)(xt + (size_t)(n0 + nl) * 2048 + j0 + ch);
  dst[0] = ((const float4*)tmp)[0];
  dst[1] = ((const float4*)tmp)[1];
}

// btc[s][d][k] = k<128 ? adaptive_w[s][d][k] : prior_fwd_w[s][d][k-128]  (bf16)
__global__ void convw_k(const float* __restrict__ pw, const float* __restrict__ aw,
                        u16* __restrict__ btc) {
  const int idx = blockIdx.x * 256 + threadIdx.x;   // < 2*128*256
  const int k = idx & 255, d = (idx >> 8) & 127, s = idx >> 15;
  const float v = (k < 128) ? aw[(s * 128 + d) * 128 + k] : pw[(s * 128 + d) * 128 + (k - 128)];
  btc[idx] = f2bf(v);
}

__global__ void pooled1_k(const float* __restrict__ x, float* __restrict__ pooled) {
  const int i = blockIdx.x, t = threadIdx.x;
  const int c = t & 127, h = t >> 7;
  const float* base = x + (size_t)i * 8192 + c;
  float s = 0.f;
  for (int k = h * 32; k < h * 32 + 32; k++) s += base[(size_t)k * 128];
  __shared__ float red[256];
  red[t] = s; __syncthreads();
  if (t < 128) pooled[i * 128 + t] = (red[t] + red[t + 128]) * (1.f / 64.f);
}

// pooled over the Xa half (cols 0..127) of the packed [Xa|Xf] bf16 buffer (ld=256)
__global__ void pooled2_k(const u16* __restrict__ comb, float* __restrict__ pooled) {
  const int i = blockIdx.x, t = threadIdx.x;
  const int c = t & 127, h = t >> 7;
  const u16* base = comb + (size_t)i * 64 * 256 + c;
  float s = 0.f;
  for (int k = h * 32; k < h * 32 + 32; k++) s += bf2f(base[(size_t)k * 256]);
  __shared__ float red[256];
  red[t] = s; __syncthreads();
  if (t < 128) pooled[i * 128 + t] = (red[t] + red[t + 128]) * (1.f / 64.f);
}

// e3 = pooled @ W3^T, f = (pooled @ W1^T) @ W2^T   (row-local, block=64 threads per row)
__global__ void epre_k(const float* __restrict__ pooled,
                       const float* __restrict__ W1, const float* __restrict__ W2,
                       const float* __restrict__ W3,
                       float* __restrict__ e3, float* __restrict__ f) {
  const int i = blockIdx.x, d = threadIdx.x;   // d in [0,64)
  __shared__ float pr[128], e1s[64];
  pr[d] = pooled[i * 128 + d];
  pr[d + 64] = pooled[i * 128 + 64 + d];
  __syncthreads();
  float s1 = 0.f, s3 = 0.f;
  for (int c = 0; c < 128; c++) {
    const float p = pr[c];
    s1 += p * W1[d * 128 + c];
    s3 += p * W3[d * 128 + c];
  }
  e1s[d] = s1;
  e3[i * 64 + d] = s3;
  __syncthreads();
  float sf = 0.f;
  for (int dd = 0; dd < 64; dd++) sf += e1s[dd] * W2[d * 64 + dd];
  f[i * 64 + d] = sf;
}

__device__ __forceinline__ float blkRedSum(float v, volatile float* w4, int t) {
#pragma unroll
  for (int o = 32; o; o >>= 1) v += __shfl_down(v, o);
  if ((t & 63) == 0) w4[t >> 6] = v;
  __syncthreads();
  v = w4[0] + w4[1] + w4[2] + w4[3];
  __syncthreads();
  return v;
}
__device__ __forceinline__ float blkRedMax(float v, volatile float* w4, int t) {
#pragma unroll
  for (int o = 32; o; o >>= 1) v = fmaxf(v, __shfl_down(v, o));
  if ((t & 63) == 0) w4[t >> 6] = v;
  __syncthreads();
  v = fmaxf(fmaxf(w4[0], w4[1]), fmaxf(w4[2], w4[3]));
  __syncthreads();
  return v;
}

// one block per row: logits -> softmax -> top-p (bisection on exp-values) -> renorm -> bf16
__global__ void attn_k(const float* __restrict__ f, const float* __restrict__ e3,
                       u16* __restrict__ attnb) {
  const int i = blockIdx.x, t = threadIdx.x;
  __shared__ float Fi[64];
  __shared__ float w4[4];
  if (t < 64) Fi[t] = f[i * 64 + t];
  __syncthreads();
  float E[8], l[8];
  float mx = -1e30f;
#pragma unroll
  for (int u = 0; u < 8; u++) {
    const int j = t + u * 256;
    const float4* er = (const float4*)(e3 + j * 64);
    float s = 0.f;
#pragma unroll
    for (int q = 0; q < 16; q++) {
      const float4 v = er[q];
      s += v.x * Fi[4 * q] + v.y * Fi[4 * q + 1] + v.z * Fi[4 * q + 2] + v.w * Fi[4 * q + 3];
    }
    l[u] = s;
    mx = fmaxf(mx, s);
  }
  mx = blkRedMax(mx, w4, t);
  float S = 0.f;
#pragma unroll
  for (int u = 0; u < 8; u++) { E[u] = expf(l[u] - mx); S += E[u]; }
  S = blkRedSum(S, w4, t);
  const float target = 0.9f * S;
  float lo = 0.f, hi = 1.f;
  for (int it = 0; it < 40; ++it) {
    const float mid = 0.5f * (lo + hi);
    float g = 0.f;
#pragma unroll
    for (int u = 0; u < 8; u++) g += (E[u] > mid) ? E[u] : 0.f;
    g = blkRedSum(g, w4, t);
    if (g < target) hi = mid; else lo = mid;   // invariant: G(lo) >= target > G(hi)
  }
  float Sk = 0.f;
#pragma unroll
  for (int u = 0; u < 8; u++) Sk += (E[u] > lo) ? E[u] : 0.f;
  Sk = blkRedSum(Sk, w4, t);
  const float inv = 1.f / Sk;   // Sk >= 1 (max element always kept)
#pragma unroll
  for (int u = 0; u < 8; u++)
    attnb[(size_t)i * 2048 + t + u * 256] = f2bf(E[u] > lo ? E[u] * inv : 0.f);
}

// out = LN(x + gate*residual)*gamma + beta ; residual lives in `out` (in-place)
__global__ void ln_k(const float* __restrict__ x, float* __restrict__ out,
                     const float* __restrict__ gamma, const float* __restrict__ beta,
                     const float* __restrict__ alpha) {
  const int wid = threadIdx.x >> 6, lane = threadIdx.x & 63;
  const float gate = 1.f / (1.f + expf(-alpha[0]));
  const float2 g = ((const float2*)gamma)[lane];
  const float2 b = ((const float2*)beta)[lane];
#pragma unroll
  for (int rr = 0; rr < 2; ++rr) {
    const size_t row = (size_t)blockIdx.x * 8 + wid * 2 + rr;
    const float2 xv = ((const float2*)(x + row * 128))[lane];
    float2* op = (float2*)(out + row * 128);
    const float2 rv = op[lane];
    const float h0 = xv.x + gate * rv.x, h1 = xv.y + gate * rv.y;
    float s = h0 + h1;
#pragma unroll
    for (int o = 32; o; o >>= 1) s += __shfl_down(s, o);
    const float mu = __shfl(s, 0) * (1.f / 128.f);
    const float d0 = h0 - mu, d1 = h1 - mu;
    float vs = d0 * d0 + d1 * d1;
#pragma unroll
    for (int o = 32; o; o >>= 1) vs += __shfl_down(vs, o);
    const float rstd = rsqrtf(__shfl(vs, 0) * (1.f / 128.f) + 1e-5f);
    float2 ov;
    ov.x = d0 * rstd * g.x + b.x;
    ov.y = d1 * rstd * g.y + b.y;
    op[lane] = ov;
  }
}

// ---------------------------------------------------------------------------
extern "C" void kernel_launch(void* const* d_in, const int* in_sizes, int n_in,
                              void* d_out, int out_size, void* d_ws, size_t ws_size,
                              hipStream_t stream) {
  const float* x     = (const float*)d_in[0];
  const float* prior = (const float*)d_in[1];
  const float* W1    = (const float*)d_in[2];
  const float* W2    = (const float*)d_in[3];
  const float* W3    = (const float*)d_in[4];
  const float* Pw    = (const float*)d_in[5];
  const float* Aw    = (const float*)d_in[6];
  const float* gamma = (const float*)d_in[7];
  const float* beta  = (const float*)d_in[8];
  const float* alpha = (const float*)d_in[9];
  float* out = (float*)d_out;

  char* w = (char*)d_ws;
  u16*   Xt_x   = (u16*)(w);                 // 8192x2048 bf16 = 33.55 MB
  u16*   XtA    = (u16*)(w + 33554432);      // 33.55 MB
  u16*   XtF    = (u16*)(w + 67108864);      // 33.55 MB
  u16*   comb   = (u16*)(w + 100663296);     // 131072x256 bf16 [Xa|Xf] = 67.1 MB
  u16*   priorS = (u16*)(w + 167772160);     // 8.39 MB
  u16*   attnb  = (u16*)(w + 176160768);     // 8.39 MB
  float* pooled = (float*)(w + 184549376);   // 1.05 MB
  float* e3     = (float*)(w + 185597952);   // 0.52 MB
  float* fbuf   = (float*)(w + 186122240);   // 0.52 MB
  float* rs     = (float*)(w + 186646528);   // 8 KB
  u16*   btc    = (u16*)(w + 186654720);     // 2x128x256 bf16 = 131 KB
  (void)in_sizes; (void)n_in; (void)ws_size;

  hipMemsetAsync(d_out, 0, (size_t)out_size * 4, stream);  // residual accumulator

  rowsum_k   <<<2048, 256, 0, stream>>>(prior, rs);
  convprior_k<<<4096, 256, 0, stream>>>((const float4*)prior, rs, (ushort4*)priorS);
  convx_k    <<<dim3(128, 32), 256, 0, stream>>>(x, Xt_x);
  convw_k    <<<256, 256, 0, stream>>>(Pw, Aw, btc);

  // step 1 attention
  pooled1_k  <<<2048, 256, 0, stream>>>(x, pooled);
  epre_k     <<<2048, 64, 0, stream>>>(pooled, W1, W2, W3, e3, fbuf);
  attn_k     <<<2048, 256, 0, stream>>>(fbuf, e3, attnb);

  // Xa1 = attn1 @ x ; Xf1 = Rf @ x   (write packed [Xa|Xf] bf16 + transposed copies)
  gemm_bt<1><<<dim3(64, 16), 256, 34816, stream>>>(attnb,  Xt_x, 2048, 8192, 2048,
                                                   nullptr, comb, 256, 0,   XtA, 2048);
  gemm_bt<1><<<dim3(64, 16), 256, 34816, stream>>>(priorS, Xt_x, 2048, 8192, 2048,
                                                   nullptr, comb, 256, 128, XtF, 2048);

  // step 2 attention (pooled over Xa1)
  pooled2_k  <<<2048, 256, 0, stream>>>(comb, pooled);
  epre_k     <<<2048, 64, 0, stream>>>(pooled, W1, W2, W3, e3, fbuf);
  attn_k     <<<2048, 256, 0, stream>>>(fbuf, e3, attnb);

  // residual += Xa1 @ Aw1^T + Xf1 @ Pw1^T   (one tall GEMM over packed K=256)
  gemm_bt<0><<<dim3(1, 1024), 256, 16384, stream>>>(comb, btc, 131072, 128, 256,
                                                    out, nullptr, 0, 0, nullptr, 0);

  // Xa2 = attn2 @ Xa1 ; Xf2 = Rf @ Xf1   (overwrite packed buffer)
  gemm_bt<2><<<dim3(64, 16), 256, 34816, stream>>>(attnb,  XtA, 2048, 8192, 2048,
                                                   nullptr, comb, 256, 0,   nullptr, 0);
  gemm_bt<2><<<dim3(64, 16), 256, 34816, stream>>>(priorS, XtF, 2048, 8192, 2048,
                                                   nullptr, comb, 256, 128, nullptr, 0);

  // residual += Xa2 @ Aw2^T + Xf2 @ Pw2^T
  gemm_bt<0><<<dim3(1, 1024), 256, 16384, stream>>>(comb, btc + 32768, 131072, 128, 256,
                                                    out, nullptr, 0, 0, nullptr, 0);

  ln_k<<<16384, 256, 0, stream>>>(x, out, gamma, beta, alpha);
}

// Round 2
// 900.595 us; speedup vs baseline: 1.2486x; 1.2486x over previous
//
#include <hip/hip_runtime.h>

typedef unsigned short u16;
typedef __attribute__((ext_vector_type(8))) short short8;
typedef __attribute__((ext_vector_type(4))) float f32x4;

#define AS1 __attribute__((address_space(1)))
#define AS3 __attribute__((address_space(3)))

__device__ __forceinline__ void async_cp16(const void* g, void* l) {
  __builtin_amdgcn_global_load_lds((const AS1 unsigned int*)g, (AS3 unsigned int*)l, 16, 0, 0);
}

__device__ __forceinline__ u16 f2bf(float f) {
  union { float f; unsigned u; } v; v.f = f;
  unsigned r = v.u + 0x7fffu + ((v.u >> 16) & 1u);
  return (u16)(r >> 16);
}
__device__ __forceinline__ float bf2f(u16 h) {
  union { unsigned u; float f; } v; v.u = ((unsigned)h) << 16;
  return v.f;
}

// ---------------------------------------------------------------------------
// GEMM: C[M,N] = A[M,K] @ B^T[N,K]^T, bf16 inputs, fp32 accumulate.
// MODE 0: Cf[m,n] += acc (f32, ldc=N)           -- tall delta GEMMs into residual
// MODE 1: bf16 row-major into Crow (packed [Xa|Xf] layout) + bf16 transposed into Ct
// MODE 2: bf16 row-major into Crow only
// MODE 3: Cf[m,n] = acc (f32, ldc=N)            -- logits
// Block 256 = 4 waves (2x2), tile 128x128, BK=32, 16x16x32 bf16 MFMA.
// ---------------------------------------------------------------------------
template<int MODE>
__global__ __launch_bounds__(256) void gemm_bt(
    const u16* __restrict__ A, const u16* __restrict__ B,
    int M, int N, int K,
    float* __restrict__ Cf,
    u16* __restrict__ Crow, int crow_ld, int crow_coloff,
    u16* __restrict__ Ct, int ct_ld)
{
  extern __shared__ char smem[];
  u16* sA = (u16*)smem;            // [128][32] bf16, row-major, no pad (global_load_lds layout)
  u16* sB = (u16*)(smem + 8192);   // [128][32]
  const int tid  = threadIdx.x;
  const int lane = tid & 63;
  const int wid  = tid >> 6;
  const int m0 = blockIdx.y * 128;
  const int n0 = blockIdx.x * 128;
  const int wm = (wid >> 1) * 64;
  const int wn = (wid & 1) * 64;
  const int ml = lane & 15;
  const int qd = lane >> 4;

  f32x4 acc[4][4];
  const f32x4 zero = {0.f, 0.f, 0.f, 0.f};
#pragma unroll
  for (int i = 0; i < 4; i++)
#pragma unroll
    for (int j = 0; j < 4; j++) acc[i][j] = zero;

  // staging: thread t loads 16B at global row (t>>2), k-chunk (t&3)*8 -> LDS byte t*16
  const int r4 = tid >> 2;
  const int c4 = (tid & 3) * 8;
  const u16* gA0 = A + (size_t)(m0 + r4) * K + c4;
  const u16* gA1 = A + (size_t)(m0 + 64 + r4) * K + c4;
  const u16* gB0 = B + (size_t)(n0 + r4) * K + c4;
  const u16* gB1 = B + (size_t)(n0 + 64 + r4) * K + c4;
  u16* lA0 = sA + wid * 512;          // wave-uniform base; HW adds lane*16B
  u16* lA1 = sA + 2048 + wid * 512;
  u16* lB0 = sB + wid * 512;
  u16* lB1 = sB + 2048 + wid * 512;

  for (int k0 = 0; k0 < K; k0 += 32) {
    async_cp16(gA0 + k0, lA0);
    async_cp16(gA1 + k0, lA1);
    async_cp16(gB0 + k0, lB0);
    async_cp16(gB1 + k0, lB1);
    __syncthreads();   // drains vmcnt -> LDS tiles ready
    short8 af[4], bfr[4];
#pragma unroll
    for (int i = 0; i < 4; i++)
      af[i] = *(const short8*)(sA + (wm + i * 16 + ml) * 32 + qd * 8);
#pragma unroll
    for (int j = 0; j < 4; j++)
      bfr[j] = *(const short8*)(sB + (wn + j * 16 + ml) * 32 + qd * 8);
#pragma unroll
    for (int i = 0; i < 4; i++)
#pragma unroll
      for (int j = 0; j < 4; j++)
        acc[i][j] = __builtin_amdgcn_mfma_f32_16x16x32_bf16(af[i], bfr[j], acc[i][j], 0, 0, 0);
    __syncthreads();   // protect LDS from next iter's staging
  }

  if constexpr (MODE == 0 || MODE == 3) {
#pragma unroll
    for (int i = 0; i < 4; i++) {
      const int mr = m0 + wm + i * 16 + qd * 4;
#pragma unroll
      for (int j = 0; j < 4; j++) {
        const int nc = n0 + wn + j * 16 + ml;
        float* p = Cf + (size_t)mr * N + nc;
#pragma unroll
        for (int r = 0; r < 4; r++) {
          if constexpr (MODE == 0) p[(size_t)r * N] += acc[i][j][r];
          else                     p[(size_t)r * N]  = acc[i][j][r];
        }
      }
    }
  } else {
    u16* T = (u16*)smem;  // [128][136] bf16 bounce buffer (aliases sA/sB; loop ended with barrier)
    // phase 1: row-major bf16 into packed Crow: row = m*(N/128)+(n0/128), col = n%128 + coloff
#pragma unroll
    for (int i = 0; i < 4; i++)
#pragma unroll
      for (int j = 0; j < 4; j++)
#pragma unroll
        for (int r = 0; r < 4; r++)
          T[(wm + i * 16 + qd * 4 + r) * 136 + wn + j * 16 + ml] = f2bf(acc[i][j][r]);
    __syncthreads();
    {
      const int row = tid >> 1, half = tid & 1;
      const size_t crow = (size_t)(m0 + row) * (N >> 7) + (n0 >> 7);
      u16* dst = Crow + crow * (size_t)crow_ld + crow_coloff + half * 64;
      const u16* src = T + row * 136 + half * 64;
#pragma unroll
      for (int u = 0; u < 8; u++) ((float4*)dst)[u] = ((const float4*)src)[u];
    }
    if constexpr (MODE == 1) {
      __syncthreads();
      // phase 2: transposed bf16: Ct[n][m]
#pragma unroll
      for (int i = 0; i < 4; i++)
#pragma unroll
        for (int j = 0; j < 4; j++)
#pragma unroll
          for (int r = 0; r < 4; r++)
            T[(wn + j * 16 + ml) * 136 + wm + i * 16 + qd * 4 + r] = f2bf(acc[i][j][r]);
      __syncthreads();
      const int row = tid >> 1, half = tid & 1;
      u16* dst = Ct + (size_t)(n0 + row) * ct_ld + m0 + half * 64;
      const u16* src = T + row * 136 + half * 64;
#pragma unroll
      for (int u = 0; u < 8; u++) ((float4*)dst)[u] = ((const float4*)src)[u];
    }
  }
}

// ---------------------------------------------------------------------------
// small kernels
// ---------------------------------------------------------------------------
__global__ void rowsum_k(const float* __restrict__ prior, float* __restrict__ rs) {
  const int i = blockIdx.x, t = threadIdx.x;
  const float* p = prior + (size_t)i * 2048;
  float s = 0.f;
  for (int j = t; j < 2048; j += 256) s += p[j];
  __shared__ float red[256];
  red[t] = s; __syncthreads();
  for (int o = 128; o; o >>= 1) { if (t < o) red[t] += red[t + o]; __syncthreads(); }
  if (t == 0) rs[i] = red[0];
}

__global__ void convprior_k(const float4* __restrict__ prior, const float* __restrict__ rs,
                            ushort4* __restrict__ dst) {
  const int idx = blockIdx.x * 256 + threadIdx.x;   // < 2048*2048/4
  const float inv = 1.0f / rs[idx >> 9];
  const float4 v = prior[idx];
  ushort4 o;
  o.x = f2bf(v.x * inv); o.y = f2bf(v.y * inv); o.z = f2bf(v.z * inv); o.w = f2bf(v.w * inv);
  dst[idx] = o;
}

// x (2048 x 8192 f32) -> Xt (8192 x 2048 bf16), tiled 64x64 transpose
__global__ void convx_k(const float* __restrict__ x, u16* __restrict__ xt) {
  __shared__ float S[64][65];
  const int t = threadIdx.x;
  const int j0 = blockIdx.y * 64;
  const int n0 = blockIdx.x * 64;
  const int rr = t >> 4, cc = (t & 15) * 4;
#pragma unroll
  for (int p = 0; p < 4; p++) {
    const float4 v = *(const float4*)(x + (size_t)(j0 + rr + p * 16) * 8192 + n0 + cc);
    S[rr + p * 16][cc + 0] = v.x; S[rr + p * 16][cc + 1] = v.y;
    S[rr + p * 16][cc + 2] = v.z; S[rr + p * 16][cc + 3] = v.w;
  }
  __syncthreads();
  const int nl = t >> 2, ch = (t & 3) * 16;
  alignas(16) u16 tmp[16];
#pragma unroll
  for (int u = 0; u < 16; u++) tmp[u] = f2bf(S[ch + u][nl]);
  float4* dst = (float4*)(xt + (size_t)(n0 + nl) * 2048 + j0 + ch);
  dst[0] = ((const float4*)tmp)[0];
  dst[1] = ((const float4*)tmp)[1];
}

// btc[s][d][k] = k<128 ? adaptive_w[s][d][k] : prior_fwd_w[s][d][k-128]  (bf16)
__global__ void convw_k(const float* __restrict__ pw, const float* __restrict__ aw,
                        u16* __restrict__ btc) {
  const int idx = blockIdx.x * 256 + threadIdx.x;   // < 2*128*256
  const int k = idx & 255, d = (idx >> 8) & 127, s = idx >> 15;
  const float v = (k < 128) ? aw[(s * 128 + d) * 128 + k] : pw[(s * 128 + d) * 128 + (k - 128)];
  btc[idx] = f2bf(v);
}

__global__ void pooled1_k(const float* __restrict__ x, float* __restrict__ pooled) {
  const int i = blockIdx.x, t = threadIdx.x;
  const int c = t & 127, h = t >> 7;
  const float* base = x + (size_t)i * 8192 + c;
  float s = 0.f;
  for (int k = h * 32; k < h * 32 + 32; k++) s += base[(size_t)k * 128];
  __shared__ float red[256];
  red[t] = s; __syncthreads();
  if (t < 128) pooled[i * 128 + t] = (red[t] + red[t + 128]) * (1.f / 64.f);
}

// pooled over the Xa half (cols 0..127) of the packed [Xa|Xf] bf16 buffer (ld=256)
__global__ void pooled2_k(const u16* __restrict__ comb, float* __restrict__ pooled) {
  const int i = blockIdx.x, t = threadIdx.x;
  const int c = t & 127, h = t >> 7;
  const u16* base = comb + (size_t)i * 64 * 256 + c;
  float s = 0.f;
  for (int k = h * 32; k < h * 32 + 32; k++) s += bf2f(base[(size_t)k * 256]);
  __shared__ float red[256];
  red[t] = s; __syncthreads();
  if (t < 128) pooled[i * 128 + t] = (red[t] + red[t + 128]) * (1.f / 64.f);
}

// e3b = bf16(pooled @ W3^T), fb = bf16((pooled @ W1^T) @ W2^T)
__global__ void epre_k(const float* __restrict__ pooled,
                       const float* __restrict__ W1, const float* __restrict__ W2,
                       const float* __restrict__ W3,
                       u16* __restrict__ e3b, u16* __restrict__ fb) {
  const int i = blockIdx.x, d = threadIdx.x;   // d in [0,64)
  __shared__ float pr[128], e1s[64];
  pr[d] = pooled[i * 128 + d];
  pr[d + 64] = pooled[i * 128 + 64 + d];
  __syncthreads();
  float s1 = 0.f, s3 = 0.f;
  for (int c = 0; c < 128; c++) {
    const float p = pr[c];
    s1 += p * W1[d * 128 + c];
    s3 += p * W3[d * 128 + c];
  }
  e1s[d] = s1;
  e3b[i * 64 + d] = f2bf(s3);
  __syncthreads();
  float sf = 0.f;
  for (int dd = 0; dd < 64; dd++) sf += e1s[dd] * W2[d * 64 + dd];
  fb[i * 64 + d] = f2bf(sf);
}

// ---------------------------------------------------------------------------
// top-p over a materialized logits row. One WAVE per row; shuffle-only
// reductions (no barriers, no LDS). Lane l owns j = k*256 + l*4 + q.
// ---------------------------------------------------------------------------
__device__ __forceinline__ float waveRedSum(float v) {
#pragma unroll
  for (int o = 1; o < 64; o <<= 1) v += __shfl_xor(v, o);
  return __shfl(v, 0);   // broadcast lane 0: bit-identical threshold on all lanes
}
__device__ __forceinline__ float waveRedMax(float v) {
#pragma unroll
  for (int o = 1; o < 64; o <<= 1) v = fmaxf(v, __shfl_xor(v, o));
  return __shfl(v, 0);
}

__global__ __launch_bounds__(256) void topp_k(const float* __restrict__ logits,
                                              u16* __restrict__ attnb) {
  const int w = threadIdx.x >> 6, l = threadIdx.x & 63;
  const int i = blockIdx.x * 4 + w;
  const float4* row = (const float4*)(logits + (size_t)i * 2048);
  float E[32];
  float mx = -1e30f;
#pragma unroll
  for (int k = 0; k < 8; k++) {
    const float4 v = row[k * 64 + l];
    E[k * 4 + 0] = v.x; E[k * 4 + 1] = v.y; E[k * 4 + 2] = v.z; E[k * 4 + 3] = v.w;
    mx = fmaxf(fmaxf(mx, fmaxf(v.x, v.y)), fmaxf(v.z, v.w));
  }
  mx = waveRedMax(mx);
  float S = 0.f;
#pragma unroll
  for (int u = 0; u < 32; u++) { E[u] = __expf(E[u] - mx); S += E[u]; }
  S = waveRedSum(S);
  const float target = 0.9f * S;
  float lo = 0.f, hi = 1.f;
  for (int it = 0; it < 32; ++it) {
    const float mid = 0.5f * (lo + hi);
    float g = 0.f;
#pragma unroll
    for (int u = 0; u < 32; u++) g += (E[u] > mid) ? E[u] : 0.f;
    g = waveRedSum(g);
    const bool below = (g < target);
    hi = below ? mid : hi;       // invariant: G(lo) >= target > G(hi)
    lo = below ? lo : mid;
  }
  float Sk = 0.f;
#pragma unroll
  for (int u = 0; u < 32; u++) Sk += (E[u] > lo) ? E[u] : 0.f;
  Sk = waveRedSum(Sk);
  const float inv = 1.f / Sk;    // >=1 element (the max) always kept
  u16* dst = attnb + (size_t)i * 2048;
#pragma unroll
  for (int k = 0; k < 8; k++) {
    ushort4 o;
    o.x = f2bf(E[k * 4 + 0] > lo ? E[k * 4 + 0] * inv : 0.f);
    o.y = f2bf(E[k * 4 + 1] > lo ? E[k * 4 + 1] * inv : 0.f);
    o.z = f2bf(E[k * 4 + 2] > lo ? E[k * 4 + 2] * inv : 0.f);
    o.w = f2bf(E[k * 4 + 3] > lo ? E[k * 4 + 3] * inv : 0.f);
    *(ushort4*)(dst + k * 256 + l * 4) = o;
  }
}

// out = LN(x + gate*residual)*gamma + beta ; residual lives in `out` (in-place)
__global__ void ln_k(const float* __restrict__ x, float* __restrict__ out,
                     const float* __restrict__ gamma, const float* __restrict__ beta,
                     const float* __restrict__ alpha) {
  const int wid = threadIdx.x >> 6, lane = threadIdx.x & 63;
  const float gate = 1.f / (1.f + expf(-alpha[0]));
  const float2 g = ((const float2*)gamma)[lane];
  const float2 b = ((const float2*)beta)[lane];
#pragma unroll
  for (int rr = 0; rr < 2; ++rr) {
    const size_t row = (size_t)blockIdx.x * 8 + wid * 2 + rr;
    const float2 xv = ((const float2*)(x + row * 128))[lane];
    float2* op = (float2*)(out + row * 128);
    const float2 rv = op[lane];
    const float h0 = xv.x + gate * rv.x, h1 = xv.y + gate * rv.y;
    float s = h0 + h1;
#pragma unroll
    for (int o = 32; o; o >>= 1) s += __shfl_down(s, o);
    const float mu = __shfl(s, 0) * (1.f / 128.f);
    const float d0 = h0 - mu, d1 = h1 - mu;
    float vs = d0 * d0 + d1 * d1;
#pragma unroll
    for (int o = 32; o; o >>= 1) vs += __shfl_down(vs, o);
    const float rstd = rsqrtf(__shfl(vs, 0) * (1.f / 128.f) + 1e-5f);
    float2 ov;
    ov.x = d0 * rstd * g.x + b.x;
    ov.y = d1 * rstd * g.y + b.y;
    op[lane] = ov;
  }
}

// ---------------------------------------------------------------------------
extern "C" void kernel_launch(void* const* d_in, const int* in_sizes, int n_in,
                              void* d_out, int out_size, void* d_ws, size_t ws_size,
                              hipStream_t stream) {
  const float* x     = (const float*)d_in[0];
  const float* prior = (const float*)d_in[1];
  const float* W1    = (const float*)d_in[2];
  const float* W2    = (const float*)d_in[3];
  const float* W3    = (const float*)d_in[4];
  const float* Pw    = (const float*)d_in[5];
  const float* Aw    = (const float*)d_in[6];
  const float* gamma = (const float*)d_in[7];
  const float* beta  = (const float*)d_in[8];
  const float* alpha = (const float*)d_in[9];
  float* out = (float*)d_out;

  char* w = (char*)d_ws;
  u16*   Xt_x   = (u16*)(w);                 // 8192x2048 bf16 = 33.55 MB
  u16*   XtA    = (u16*)(w + 33554432);      // 33.55 MB
  u16*   XtF    = (u16*)(w + 67108864);      // 33.55 MB
  u16*   comb   = (u16*)(w + 100663296);     // 131072x256 bf16 [Xa|Xf] = 67.1 MB
  u16*   priorS = (u16*)(w + 167772160);     // 8.39 MB
  u16*   attnb  = (u16*)(w + 176160768);     // 8.39 MB
  float* pooled = (float*)(w + 184549376);   // 1.05 MB
  u16*   e3b    = (u16*)(w + 185597952);     // 256 KB (old e3 slot)
  u16*   fb     = (u16*)(w + 186122240);     // 256 KB (old fbuf slot)
  float* rs     = (float*)(w + 186646528);   // 8 KB
  u16*   btc    = (u16*)(w + 186654720);     // 2x128x256 bf16 = 131 KB
  // logits buffers ALIAS dead/not-yet-live regions (no extra ws):
  float* logits1 = (float*)(w + 33554432);   // XtA region: written only after topp1 consumed
  float* logits2 = (float*)(w);              // Xt_x region: dead after the MODE-1 GEMMs
  (void)in_sizes; (void)n_in; (void)ws_size;

  hipMemsetAsync(d_out, 0, (size_t)out_size * 4, stream);  // residual accumulator

  rowsum_k   <<<2048, 256, 0, stream>>>(prior, rs);
  convprior_k<<<4096, 256, 0, stream>>>((const float4*)prior, rs, (ushort4*)priorS);
  convx_k    <<<dim3(128, 32), 256, 0, stream>>>(x, Xt_x);
  convw_k    <<<256, 256, 0, stream>>>(Pw, Aw, btc);

  // step 1 attention: pooled -> (fb, e3b) -> logits GEMM -> wave top-p
  pooled1_k  <<<2048, 256, 0, stream>>>(x, pooled);
  epre_k     <<<2048, 64, 0, stream>>>(pooled, W1, W2, W3, e3b, fb);
  gemm_bt<3> <<<dim3(16, 16), 256, 16384, stream>>>(fb, e3b, 2048, 2048, 64,
                                                    logits1, nullptr, 0, 0, nullptr, 0);
  topp_k     <<<512, 256, 0, stream>>>(logits1, attnb);

  // Xa1 = attn1 @ x ; Xf1 = Rf @ x   (write packed [Xa|Xf] bf16 + transposed copies)
  gemm_bt<1><<<dim3(64, 16), 256, 34816, stream>>>(attnb,  Xt_x, 2048, 8192, 2048,
                                                   nullptr, comb, 256, 0,   XtA, 2048);
  gemm_bt<1><<<dim3(64, 16), 256, 34816, stream>>>(priorS, Xt_x, 2048, 8192, 2048,
                                                   nullptr, comb, 256, 128, XtF, 2048);

  // step 2 attention (pooled over Xa1); logits2 aliases the now-dead Xt_x
  pooled2_k  <<<2048, 256, 0, stream>>>(comb, pooled);
  epre_k     <<<2048, 64, 0, stream>>>(pooled, W1, W2, W3, e3b, fb);
  gemm_bt<3> <<<dim3(16, 16), 256, 16384, stream>>>(fb, e3b, 2048, 2048, 64,
                                                    logits2, nullptr, 0, 0, nullptr, 0);
  topp_k     <<<512, 256, 0, stream>>>(logits2, attnb);

  // residual += Xa1 @ Aw1^T + Xf1 @ Pw1^T   (one tall GEMM over packed K=256)
  gemm_bt<0><<<dim3(1, 1024), 256, 16384, stream>>>(comb, btc, 131072, 128, 256,
                                                    out, nullptr, 0, 0, nullptr, 0);

  // Xa2 = attn2 @ Xa1 ; Xf2 = Rf @ Xf1   (overwrite packed buffer)
  gemm_bt<2><<<dim3(64, 16), 256, 34816, stream>>>(attnb,  XtA, 2048, 8192, 2048,
                                                   nullptr, comb, 256, 0,   nullptr, 0);
  gemm_bt<2><<<dim3(64, 16), 256, 34816, stream>>>(priorS, XtF, 2048, 8192, 2048,
                                                   nullptr, comb, 256, 128, nullptr, 0);

  // residual += Xa2 @ Aw2^T + Xf2 @ Pw2^T
  gemm_bt<0><<<dim3(1, 1024), 256, 16384, stream>>>(comb, btc + 32768, 131072, 128, 256,
                                                    out, nullptr, 0, 0, nullptr, 0);

  ln_k<<<16384, 256, 0, stream>>>(x, out, gamma, beta, alpha);
}

// Round 4
// 703.679 us; speedup vs baseline: 1.5980x; 1.2798x over previous
//
#include <hip/hip_runtime.h>

typedef unsigned short u16;
typedef __attribute__((ext_vector_type(8))) short short8;
typedef __attribute__((ext_vector_type(4))) float f32x4;
typedef __attribute__((ext_vector_type(16))) float f32x16;

#define AS1 __attribute__((address_space(1)))
#define AS3 __attribute__((address_space(3)))

__device__ __forceinline__ void async_cp16(const void* g, void* l) {
  __builtin_amdgcn_global_load_lds((const AS1 unsigned int*)g, (AS3 unsigned int*)l, 16, 0, 0);
}

__device__ __forceinline__ u16 f2bf(float f) {
  union { float f; unsigned u; } v; v.f = f;
  unsigned r = v.u + 0x7fffu + ((v.u >> 16) & 1u);
  return (u16)(r >> 16);
}
__device__ __forceinline__ float bf2f(u16 h) {
  union { unsigned u; float f; } v; v.u = ((unsigned)h) << 16;
  return v.f;
}

// ---------------------------------------------------------------------------
// Big diffusion GEMM: C[M,N] = A[M,K] @ B^T[N,K]^T, 32x32x16 bf16 MFMA.
// Block 256 = 4 waves (2x2 of 64x64), tile 128x128, BK=32.
// K-chunk staging is XOR-swizzled (p = (r&3)^((r>>2)&3)) to spread fragment
// ds_read_b128 across bank-quads; swizzle applied to the GLOBAL source since
// the LDS dest of global_load_lds is fixed (wave base + lane*16B).
// MODE 1: bf16 row-major into packed Crow + bf16 transposed into Ct
// MODE 2: bf16 row-major into Crow only
// ---------------------------------------------------------------------------
template<int MODE>
__global__ __launch_bounds__(256, 3) void gemm32(
    const u16* __restrict__ A, const u16* __restrict__ B,
    int M, int N, int K,
    u16* __restrict__ Crow, int crow_ld, int crow_coloff,
    u16* __restrict__ Ct, int ct_ld)
{
  __shared__ u16 smem[8704];       // 17408 B: staging 16384 B, epilogue T 64x136
  u16* sA = smem;                  // [128][32]
  u16* sB = smem + 4096;           // [128][32]
  const int tid  = threadIdx.x;
  const int lane = tid & 63;
  const int wid  = tid >> 6;
  const int m0 = blockIdx.y * 128;
  const int n0 = blockIdx.x * 128;
  const int wm = (wid >> 1) * 64;
  const int wn = (wid & 1) * 64;
  const int l31  = lane & 31;
  const int half = lane >> 5;
  const int pl   = (l31 & 3) ^ ((l31 >> 2) & 3);   // read-side swizzle (row bits 0..3)

  f32x16 acc[2][2];
#pragma unroll
  for (int i = 0; i < 2; i++)
#pragma unroll
    for (int j = 0; j < 2; j++)
#pragma unroll
      for (int r = 0; r < 16; r++) acc[i][j][r] = 0.f;

  // staging: thread t = r*4+cc stages LDS slot (row r, chunk cc) <- global chunk cc^p(r)
  const int r4 = tid >> 2;
  const int cc = tid & 3;
  const int g8 = (cc ^ ((r4 & 3) ^ ((r4 >> 2) & 3))) * 8;
  const u16* gA0 = A + (size_t)(m0 + r4) * K + g8;
  const u16* gA1 = A + (size_t)(m0 + 64 + r4) * K + g8;
  const u16* gB0 = B + (size_t)(n0 + r4) * K + g8;
  const u16* gB1 = B + (size_t)(n0 + 64 + r4) * K + g8;
  u16* lA0 = sA + wid * 512;
  u16* lA1 = sA + 2048 + wid * 512;
  u16* lB0 = sB + wid * 512;
  u16* lB1 = sB + 2048 + wid * 512;

  for (int k0 = 0; k0 < K; k0 += 32) {
    async_cp16(gA0 + k0, lA0);
    async_cp16(gA1 + k0, lA1);
    async_cp16(gB0 + k0, lB0);
    async_cp16(gB1 + k0, lB1);
    __syncthreads();
#pragma unroll
    for (int s = 0; s < 2; s++) {
      const int kc = ((s * 2 + half) ^ pl) * 8;   // swizzled chunk offset (u16)
      short8 aF[2], bF[2];
#pragma unroll
      for (int i = 0; i < 2; i++)
        aF[i] = *(const short8*)(sA + (wm + i * 32 + l31) * 32 + kc);
#pragma unroll
      for (int j = 0; j < 2; j++)
        bF[j] = *(const short8*)(sB + (wn + j * 32 + l31) * 32 + kc);
#pragma unroll
      for (int i = 0; i < 2; i++)
#pragma unroll
        for (int j = 0; j < 2; j++)
          acc[i][j] = __builtin_amdgcn_mfma_f32_32x32x16_bf16(aF[i], bF[j], acc[i][j], 0, 0, 0);
    }
    __syncthreads();
  }

  // C/D layout (m74/m101): col = lane&31, row = (reg&3) + 8*(reg>>2) + 4*half
  u16* T = smem;   // [64][136]
  __syncthreads();
  // row-major bf16 epilogue, two 64-row passes
#pragma unroll
  for (int pass = 0; pass < 2; pass++) {
    if ((wid >> 1) == pass) {
#pragma unroll
      for (int i = 0; i < 2; i++)
#pragma unroll
        for (int j = 0; j < 2; j++)
#pragma unroll
          for (int r = 0; r < 16; r++) {
            const int rrow = i * 32 + (r & 3) + 8 * (r >> 2) + 4 * half;  // 0..63
            T[rrow * 136 + wn + j * 32 + l31] = f2bf(acc[i][j][r]);
          }
    }
    __syncthreads();
    {
      const int row = tid >> 2, q = tid & 3;       // 4 threads/row, 32 u16 each
      const size_t crow = (size_t)(m0 + pass * 64 + row) * (N >> 7) + (n0 >> 7);
      u16* dst = Crow + crow * (size_t)crow_ld + crow_coloff + q * 32;
      const u16* src = T + row * 136 + q * 32;
#pragma unroll
      for (int u = 0; u < 4; u++) ((float4*)dst)[u] = ((const float4*)src)[u];
    }
    __syncthreads();
  }
  if constexpr (MODE == 1) {
    // transposed bf16 epilogue: Ct[n][m], two 64-n passes
#pragma unroll
    for (int pass = 0; pass < 2; pass++) {
      if ((wid & 1) == pass) {
#pragma unroll
        for (int i = 0; i < 2; i++)
#pragma unroll
          for (int j = 0; j < 2; j++)
#pragma unroll
            for (int r = 0; r < 16; r++) {
              const int nloc = j * 32 + l31;                              // 0..63
              const int mcol = wm + i * 32 + (r & 3) + 8 * (r >> 2) + 4 * half;
              T[nloc * 136 + mcol] = f2bf(acc[i][j][r]);
            }
      }
      __syncthreads();
      {
        const int row = tid >> 2, q = tid & 3;
        u16* dst = Ct + (size_t)(n0 + pass * 64 + row) * ct_ld + m0 + q * 32;
        const u16* src = T + row * 136 + q * 32;
#pragma unroll
        for (int u = 0; u < 4; u++) ((float4*)dst)[u] = ((const float4*)src)[u];
      }
      __syncthreads();
    }
  }
}

// ---------------------------------------------------------------------------
// 16x16x32 GEMM (small shapes): MODE 2: bf16 row-major; MODE 3: f32 plain.
// ---------------------------------------------------------------------------
template<int MODE>
__global__ __launch_bounds__(256) void gemm_bt(
    const u16* __restrict__ A, const u16* __restrict__ B,
    int M, int N, int K,
    float* __restrict__ Cf,
    u16* __restrict__ Crow, int crow_ld, int crow_coloff)
{
  extern __shared__ char smemc[];
  u16* sA = (u16*)smemc;
  u16* sB = (u16*)(smemc + 8192);
  const int tid  = threadIdx.x;
  const int lane = tid & 63;
  const int wid  = tid >> 6;
  const int m0 = blockIdx.y * 128;
  const int n0 = blockIdx.x * 128;
  const int wm = (wid >> 1) * 64;
  const int wn = (wid & 1) * 64;
  const int ml = lane & 15;
  const int qd = lane >> 4;

  f32x4 acc[4][4];
  const f32x4 zero = {0.f, 0.f, 0.f, 0.f};
#pragma unroll
  for (int i = 0; i < 4; i++)
#pragma unroll
    for (int j = 0; j < 4; j++) acc[i][j] = zero;

  const int r4 = tid >> 2;
  const int c4 = (tid & 3) * 8;
  const u16* gA0 = A + (size_t)(m0 + r4) * K + c4;
  const u16* gA1 = A + (size_t)(m0 + 64 + r4) * K + c4;
  const u16* gB0 = B + (size_t)(n0 + r4) * K + c4;
  const u16* gB1 = B + (size_t)(n0 + 64 + r4) * K + c4;
  u16* lA0 = sA + wid * 512;
  u16* lA1 = sA + 2048 + wid * 512;
  u16* lB0 = sB + wid * 512;
  u16* lB1 = sB + 2048 + wid * 512;

  for (int k0 = 0; k0 < K; k0 += 32) {
    async_cp16(gA0 + k0, lA0);
    async_cp16(gA1 + k0, lA1);
    async_cp16(gB0 + k0, lB0);
    async_cp16(gB1 + k0, lB1);
    __syncthreads();
    short8 af[4], bfr[4];
#pragma unroll
    for (int i = 0; i < 4; i++)
      af[i] = *(const short8*)(sA + (wm + i * 16 + ml) * 32 + qd * 8);
#pragma unroll
    for (int j = 0; j < 4; j++)
      bfr[j] = *(const short8*)(sB + (wn + j * 16 + ml) * 32 + qd * 8);
#pragma unroll
    for (int i = 0; i < 4; i++)
#pragma unroll
      for (int j = 0; j < 4; j++)
        acc[i][j] = __builtin_amdgcn_mfma_f32_16x16x32_bf16(af[i], bfr[j], acc[i][j], 0, 0, 0);
    __syncthreads();
  }

  if constexpr (MODE == 3) {
#pragma unroll
    for (int i = 0; i < 4; i++) {
      const int mr = m0 + wm + i * 16 + qd * 4;
#pragma unroll
      for (int j = 0; j < 4; j++) {
        const int nc = n0 + wn + j * 16 + ml;
        float* p = Cf + (size_t)mr * N + nc;
#pragma unroll
        for (int r = 0; r < 4; r++) p[(size_t)r * N] = acc[i][j][r];
      }
    }
  } else {
    u16* T = (u16*)smemc;  // [128][136]
#pragma unroll
    for (int i = 0; i < 4; i++)
#pragma unroll
      for (int j = 0; j < 4; j++)
#pragma unroll
        for (int r = 0; r < 4; r++)
          T[(wm + i * 16 + qd * 4 + r) * 136 + wn + j * 16 + ml] = f2bf(acc[i][j][r]);
    __syncthreads();
    const int row = tid >> 1, halfr = tid & 1;
    const size_t crow = (size_t)(m0 + row) * (N >> 7) + (n0 >> 7);
    u16* dst = Crow + crow * (size_t)crow_ld + crow_coloff + halfr * 64;
    const u16* src = T + row * 136 + halfr * 64;
#pragma unroll
    for (int u = 0; u < 8; u++) ((float4*)dst)[u] = ((const float4*)src)[u];
  }
}

// ---------------------------------------------------------------------------
// small kernels
// ---------------------------------------------------------------------------
__global__ void rowsum_k(const float* __restrict__ prior, float* __restrict__ rs) {
  const int i = blockIdx.x, t = threadIdx.x;
  const float* p = prior + (size_t)i * 2048;
  float s = 0.f;
  for (int j = t; j < 2048; j += 256) s += p[j];
  __shared__ float red[256];
  red[t] = s; __syncthreads();
  for (int o = 128; o; o >>= 1) { if (t < o) red[t] += red[t + o]; __syncthreads(); }
  if (t == 0) rs[i] = red[0];
}

__global__ void convprior_k(const float4* __restrict__ prior, const float* __restrict__ rs,
                            ushort4* __restrict__ dst) {
  const int idx = blockIdx.x * 256 + threadIdx.x;
  const float inv = 1.0f / rs[idx >> 9];
  const float4 v = prior[idx];
  ushort4 o;
  o.x = f2bf(v.x * inv); o.y = f2bf(v.y * inv); o.z = f2bf(v.z * inv); o.w = f2bf(v.w * inv);
  dst[idx] = o;
}

__global__ void convx_k(const float* __restrict__ x, u16* __restrict__ xt) {
  __shared__ float S[64][65];
  const int t = threadIdx.x;
  const int j0 = blockIdx.y * 64;
  const int n0 = blockIdx.x * 64;
  const int rr = t >> 4, cxc = (t & 15) * 4;
#pragma unroll
  for (int p = 0; p < 4; p++) {
    const float4 v = *(const float4*)(x + (size_t)(j0 + rr + p * 16) * 8192 + n0 + cxc);
    S[rr + p * 16][cxc + 0] = v.x; S[rr + p * 16][cxc + 1] = v.y;
    S[rr + p * 16][cxc + 2] = v.z; S[rr + p * 16][cxc + 3] = v.w;
  }
  __syncthreads();
  const int nl = t >> 2, ch = (t & 3) * 16;
  alignas(16) u16 tmp[16];
#pragma unroll
  for (int u = 0; u < 16; u++) tmp[u] = f2bf(S[ch + u][nl]);
  float4* dst = (float4*)(xt + (size_t)(n0 + nl) * 2048 + j0 + ch);
  dst[0] = ((const float4*)tmp)[0];
  dst[1] = ((const float4*)tmp)[1];
}

__global__ void convw_k(const float* __restrict__ pw, const float* __restrict__ aw,
                        u16* __restrict__ btc) {
  const int idx = blockIdx.x * 256 + threadIdx.x;
  const int k = idx & 255, d = (idx >> 8) & 127, s = idx >> 15;
  const float v = (k < 128) ? aw[(s * 128 + d) * 128 + k] : pw[(s * 128 + d) * 128 + (k - 128)];
  btc[idx] = f2bf(v);
}

__global__ void pooled1_k(const float* __restrict__ x, float* __restrict__ pooled) {
  const int i = blockIdx.x, t = threadIdx.x;
  const int c = t & 127, h = t >> 7;
  const float* base = x + (size_t)i * 8192 + c;
  float s = 0.f;
  for (int k = h * 32; k < h * 32 + 32; k++) s += base[(size_t)k * 128];
  __shared__ float red[256];
  red[t] = s; __syncthreads();
  if (t < 128) pooled[i * 128 + t] = (red[t] + red[t + 128]) * (1.f / 64.f);
}

__global__ void pooled2_k(const u16* __restrict__ comb, float* __restrict__ pooled) {
  const int i = blockIdx.x, t = threadIdx.x;
  const int c = t & 127, h = t >> 7;
  const u16* base = comb + (size_t)i * 64 * 256 + c;
  float s = 0.f;
  for (int k = h * 32; k < h * 32 + 32; k++) s += bf2f(base[(size_t)k * 256]);
  __shared__ float red[256];
  red[t] = s; __syncthreads();
  if (t < 128) pooled[i * 128 + t] = (red[t] + red[t + 128]) * (1.f / 64.f);
}

__global__ void epre_k(const float* __restrict__ pooled,
                       const float* __restrict__ W1, const float* __restrict__ W2,
                       const float* __restrict__ W3,
                       u16* __restrict__ e3b, u16* __restrict__ fb) {
  const int i = blockIdx.x, d = threadIdx.x;
  __shared__ float pr[128], e1s[64];
  pr[d] = pooled[i * 128 + d];
  pr[d + 64] = pooled[i * 128 + 64 + d];
  __syncthreads();
  float s1 = 0.f, s3 = 0.f;
  for (int c = 0; c < 128; c++) {
    const float p = pr[c];
    s1 += p * W1[d * 128 + c];
    s3 += p * W3[d * 128 + c];
  }
  e1s[d] = s1;
  e3b[i * 64 + d] = f2bf(s3);
  __syncthreads();
  float sf = 0.f;
  for (int dd = 0; dd < 64; dd++) sf += e1s[dd] * W2[d * 64 + dd];
  fb[i * 64 + d] = f2bf(sf);
}

__device__ __forceinline__ float waveRedSum(float v) {
#pragma unroll
  for (int o = 1; o < 64; o <<= 1) v += __shfl_xor(v, o);
  return __shfl(v, 0);
}
__device__ __forceinline__ float waveRedMax(float v) {
#pragma unroll
  for (int o = 1; o < 64; o <<= 1) v = fmaxf(v, __shfl_xor(v, o));
  return __shfl(v, 0);
}

__global__ __launch_bounds__(256) void topp_k(const float* __restrict__ logits,
                                              u16* __restrict__ attnb) {
  const int w = threadIdx.x >> 6, l = threadIdx.x & 63;
  const int i = blockIdx.x * 4 + w;
  const float4* row = (const float4*)(logits + (size_t)i * 2048);
  float E[32];
  float mx = -1e30f;
#pragma unroll
  for (int k = 0; k < 8; k++) {
    const float4 v = row[k * 64 + l];
    E[k * 4 + 0] = v.x; E[k * 4 + 1] = v.y; E[k * 4 + 2] = v.z; E[k * 4 + 3] = v.w;
    mx = fmaxf(fmaxf(mx, fmaxf(v.x, v.y)), fmaxf(v.z, v.w));
  }
  mx = waveRedMax(mx);
  float S = 0.f;
#pragma unroll
  for (int u = 0; u < 32; u++) { E[u] = __expf(E[u] - mx); S += E[u]; }
  S = waveRedSum(S);
  const float target = 0.9f * S;
  float lo = 0.f, hi = 1.f;
  for (int it = 0; it < 32; ++it) {
    const float mid = 0.5f * (lo + hi);
    float g = 0.f;
#pragma unroll
    for (int u = 0; u < 32; u++) g += (E[u] > mid) ? E[u] : 0.f;
    g = waveRedSum(g);
    const bool below = (g < target);
    hi = below ? mid : hi;
    lo = below ? lo : mid;
  }
  float Sk = 0.f;
#pragma unroll
  for (int u = 0; u < 32; u++) Sk += (E[u] > lo) ? E[u] : 0.f;
  Sk = waveRedSum(Sk);
  const float inv = 1.f / Sk;
  u16* dst = attnb + (size_t)i * 2048;
#pragma unroll
  for (int k = 0; k < 8; k++) {
    ushort4 o;
    o.x = f2bf(E[k * 4 + 0] > lo ? E[k * 4 + 0] * inv : 0.f);
    o.y = f2bf(E[k * 4 + 1] > lo ? E[k * 4 + 1] * inv : 0.f);
    o.z = f2bf(E[k * 4 + 2] > lo ? E[k * 4 + 2] * inv : 0.f);
    o.w = f2bf(E[k * 4 + 3] > lo ? E[k * 4 + 3] * inv : 0.f);
    *(ushort4*)(dst + k * 256 + l * 4) = o;
  }
}

// out = LN(x + gate*(d1+d2))*gamma + beta  (deltas stored bf16)
__global__ void ln_k(const float* __restrict__ x,
                     const u16* __restrict__ d1, const u16* __restrict__ d2,
                     float* __restrict__ out,
                     const float* __restrict__ gamma, const float* __restrict__ beta,
                     const float* __restrict__ alpha) {
  const int wid = threadIdx.x >> 6, lane = threadIdx.x & 63;
  const float gate = 1.f / (1.f + expf(-alpha[0]));
  const float2 g = ((const float2*)gamma)[lane];
  const float2 b = ((const float2*)beta)[lane];
#pragma unroll
  for (int rr = 0; rr < 2; ++rr) {
    const size_t row = (size_t)blockIdx.x * 8 + wid * 2 + rr;
    const float2 xv = ((const float2*)(x + row * 128))[lane];
    const ushort2 r1 = ((const ushort2*)(d1 + row * 128))[lane];
    const ushort2 r2 = ((const ushort2*)(d2 + row * 128))[lane];
    const float h0 = xv.x + gate * (bf2f(r1.x) + bf2f(r2.x));
    const float h1 = xv.y + gate * (bf2f(r1.y) + bf2f(r2.y));
    float s = h0 + h1;
#pragma unroll
    for (int o = 32; o; o >>= 1) s += __shfl_down(s, o);
    const float mu = __shfl(s, 0) * (1.f / 128.f);
    const float d0 = h0 - mu, dd1 = h1 - mu;
    float vs = d0 * d0 + dd1 * dd1;
#pragma unroll
    for (int o = 32; o; o >>= 1) vs += __shfl_down(vs, o);
    const float rstd = rsqrtf(__shfl(vs, 0) * (1.f / 128.f) + 1e-5f);
    float2* op = (float2*)(out + row * 128);
    float2 ov;
    ov.x = d0 * rstd * g.x + b.x;
    ov.y = dd1 * rstd * g.y + b.y;
    op[lane] = ov;
  }
}

// ---------------------------------------------------------------------------
extern "C" void kernel_launch(void* const* d_in, const int* in_sizes, int n_in,
                              void* d_out, int out_size, void* d_ws, size_t ws_size,
                              hipStream_t stream) {
  const float* x     = (const float*)d_in[0];
  const float* prior = (const float*)d_in[1];
  const float* W1    = (const float*)d_in[2];
  const float* W2    = (const float*)d_in[3];
  const float* W3    = (const float*)d_in[4];
  const float* Pw    = (const float*)d_in[5];
  const float* Aw    = (const float*)d_in[6];
  const float* gamma = (const float*)d_in[7];
  const float* beta  = (const float*)d_in[8];
  const float* alpha = (const float*)d_in[9];
  float* out = (float*)d_out;

  char* w = (char*)d_ws;
  u16*   Xt_x   = (u16*)(w);                 // 8192x2048 bf16 = 33.55 MB
  u16*   XtA    = (u16*)(w + 33554432);      // 33.55 MB
  u16*   XtF    = (u16*)(w + 67108864);      // 33.55 MB
  u16*   comb   = (u16*)(w + 100663296);     // 131072x256 bf16 [Xa|Xf] = 67.1 MB
  u16*   priorS = (u16*)(w + 167772160);     // 8.39 MB
  u16*   attnb  = (u16*)(w + 176160768);     // 8.39 MB
  float* pooled = (float*)(w + 184549376);   // 1.05 MB
  u16*   e3b    = (u16*)(w + 185597952);     // 256 KB
  u16*   fb     = (u16*)(w + 186122240);     // 256 KB
  float* rs     = (float*)(w + 186646528);   // 8 KB
  u16*   btc    = (u16*)(w + 186654720);     // 2x128x256 bf16 = 131 KB
  // aliased (lifetime-disjoint) regions:
  float* logits1 = (float*)(w + 33554432);   // XtA region: dead until after topp1
  float* logits2 = (float*)(w);              // Xt_x region: dead after MODE-1 GEMMs
  u16*   d1      = (u16*)(w);                // Xt_x region: dead after topp2
  u16*   d2      = (u16*)(w + 33554432);     // XtA region: dead after step-2 Xa GEMM
  (void)in_sizes; (void)n_in; (void)ws_size;

  rowsum_k   <<<2048, 256, 0, stream>>>(prior, rs);
  convprior_k<<<4096, 256, 0, stream>>>((const float4*)prior, rs, (ushort4*)priorS);
  convx_k    <<<dim3(128, 32), 256, 0, stream>>>(x, Xt_x);
  convw_k    <<<256, 256, 0, stream>>>(Pw, Aw, btc);

  // step 1 attention
  pooled1_k  <<<2048, 256, 0, stream>>>(x, pooled);
  epre_k     <<<2048, 64, 0, stream>>>(pooled, W1, W2, W3, e3b, fb);
  gemm_bt<3> <<<dim3(16, 16), 256, 16384, stream>>>(fb, e3b, 2048, 2048, 64,
                                                    logits1, nullptr, 0, 0);
  topp_k     <<<512, 256, 0, stream>>>(logits1, attnb);

  // Xa1 = attn1 @ x ; Xf1 = Rf @ x   (packed [Xa|Xf] bf16 + transposed copies)
  gemm32<1><<<dim3(64, 16), 256, 0, stream>>>(attnb,  Xt_x, 2048, 8192, 2048,
                                              comb, 256, 0,   XtA, 2048);
  gemm32<1><<<dim3(64, 16), 256, 0, stream>>>(priorS, Xt_x, 2048, 8192, 2048,
                                              comb, 256, 128, XtF, 2048);

  // step 2 attention (pooled over Xa1); logits2 aliases the now-dead Xt_x
  pooled2_k  <<<2048, 256, 0, stream>>>(comb, pooled);
  epre_k     <<<2048, 64, 0, stream>>>(pooled, W1, W2, W3, e3b, fb);
  gemm_bt<3> <<<dim3(16, 16), 256, 16384, stream>>>(fb, e3b, 2048, 2048, 64,
                                                    logits2, nullptr, 0, 0);
  topp_k     <<<512, 256, 0, stream>>>(logits2, attnb);

  // d1 = Xa1 @ Aw1^T + Xf1 @ Pw1^T  (bf16, into dead Xt_x region; no RMW)
  gemm_bt<2><<<dim3(1, 1024), 256, 34816, stream>>>(comb, btc, 131072, 128, 256,
                                                    nullptr, d1, 128, 0);

  // Xa2 = attn2 @ Xa1 ; Xf2 = Rf @ Xf1
  gemm32<2><<<dim3(64, 16), 256, 0, stream>>>(attnb,  XtA, 2048, 8192, 2048,
                                              comb, 256, 0,   nullptr, 0);
  gemm32<2><<<dim3(64, 16), 256, 0, stream>>>(priorS, XtF, 2048, 8192, 2048,
                                              comb, 256, 128, nullptr, 0);

  // d2 = Xa2 @ Aw2^T + Xf2 @ Pw2^T  (bf16, into dead XtA region)
  gemm_bt<2><<<dim3(1, 1024), 256, 34816, stream>>>(comb, btc + 32768, 131072, 128, 256,
                                                    nullptr, d2, 128, 0);

  ln_k<<<16384, 256, 0, stream>>>(x, d1, d2, out, gamma, beta, alpha);
}

// Round 5
// 696.174 us; speedup vs baseline: 1.6152x; 1.0108x over previous
//
#include <hip/hip_runtime.h>

typedef unsigned short u16;
typedef __attribute__((ext_vector_type(8))) short short8;
typedef __attribute__((ext_vector_type(4))) float f32x4;
typedef __attribute__((ext_vector_type(16))) float f32x16;

#define AS1 __attribute__((address_space(1)))
#define AS3 __attribute__((address_space(3)))

__device__ __forceinline__ void async_cp16(const void* g, void* l) {
  __builtin_amdgcn_global_load_lds((const AS1 unsigned int*)g, (AS3 unsigned int*)l, 16, 0, 0);
}

__device__ __forceinline__ u16 f2bf(float f) {
  union { float f; unsigned u; } v; v.f = f;
  unsigned r = v.u + 0x7fffu + ((v.u >> 16) & 1u);
  return (u16)(r >> 16);
}
__device__ __forceinline__ float bf2f(u16 h) {
  union { unsigned u; float f; } v; v.u = ((unsigned)h) << 16;
  return v.f;
}

// ---------------------------------------------------------------------------
// Big diffusion GEMM: C[M,N] = A[M,K] @ B^T[N,K]^T, 32x32x16 bf16 MFMA.
// Tile 128x256, block 256 = 4 waves, each wave 64x128 (2x4 MFMA tiles).
// BK=32 -> 24KB staging/iter for 2.1 MFLOP (11.4 B/kFLOP through L2).
// XOR swizzle on k-chunks (global-source side; LDS dest of global_load_lds
// is fixed wave base + lane*16B).
// MODE 1: bf16 row-major into packed Crow + bf16 transposed into Ct
// MODE 2: bf16 row-major into Crow only
// ---------------------------------------------------------------------------
template<int MODE>
__global__ __launch_bounds__(256, 2) void gemm32(
    const u16* __restrict__ A, const u16* __restrict__ B,
    int M, int N, int K,
    u16* __restrict__ Crow, int crow_ld, int crow_coloff,
    u16* __restrict__ Ct, int ct_ld)
{
  __shared__ u16 smem[12288];      // 24576 B: sA 128x32, sB 256x32; epilogue T aliases
  u16* sA = smem;                  // [128][32]
  u16* sB = smem + 4096;           // [256][32]
  const int tid  = threadIdx.x;
  const int lane = tid & 63;
  const int wid  = tid >> 6;
  const int m0 = blockIdx.y * 128;
  const int n0 = blockIdx.x * 256;
  const int wm = (wid >> 1) * 64;       // 0 or 64
  const int wn = (wid & 1) * 128;       // 0 or 128
  const int l31  = lane & 31;
  const int half = lane >> 5;
  const int pl   = (l31 & 3) ^ ((l31 >> 2) & 3);

  f32x16 acc[2][4];
#pragma unroll
  for (int i = 0; i < 2; i++)
#pragma unroll
    for (int j = 0; j < 4; j++)
#pragma unroll
      for (int r = 0; r < 16; r++) acc[i][j][r] = 0.f;

  // staging: thread t = r*4+cc stages LDS slot (row r, chunk cc) <- global chunk cc^p(r)
  const int r4 = tid >> 2;
  const int cc = tid & 3;
  const int g8 = (cc ^ ((r4 & 3) ^ ((r4 >> 2) & 3))) * 8;
  const u16* gA0 = A + (size_t)(m0 + r4) * K + g8;
  const u16* gA1 = A + (size_t)(m0 + 64 + r4) * K + g8;
  const u16* gB0 = B + (size_t)(n0 + r4) * K + g8;
  const u16* gB1 = B + (size_t)(n0 + 64 + r4) * K + g8;
  const u16* gB2 = B + (size_t)(n0 + 128 + r4) * K + g8;
  const u16* gB3 = B + (size_t)(n0 + 192 + r4) * K + g8;
  u16* lA0 = sA + wid * 512;
  u16* lA1 = sA + 2048 + wid * 512;
  u16* lB0 = sB + wid * 512;
  u16* lB1 = sB + 2048 + wid * 512;
  u16* lB2 = sB + 4096 + wid * 512;
  u16* lB3 = sB + 6144 + wid * 512;

  for (int k0 = 0; k0 < K; k0 += 32) {
    async_cp16(gA0 + k0, lA0);
    async_cp16(gA1 + k0, lA1);
    async_cp16(gB0 + k0, lB0);
    async_cp16(gB1 + k0, lB1);
    async_cp16(gB2 + k0, lB2);
    async_cp16(gB3 + k0, lB3);
    __syncthreads();
#pragma unroll
    for (int s = 0; s < 2; s++) {
      const int kc = ((s * 2 + half) ^ pl) * 8;   // swizzled chunk offset (u16)
      short8 aF[2], bF[4];
#pragma unroll
      for (int i = 0; i < 2; i++)
        aF[i] = *(const short8*)(sA + (wm + i * 32 + l31) * 32 + kc);
#pragma unroll
      for (int j = 0; j < 4; j++)
        bF[j] = *(const short8*)(sB + (wn + j * 32 + l31) * 32 + kc);
#pragma unroll
      for (int i = 0; i < 2; i++)
#pragma unroll
        for (int j = 0; j < 4; j++)
          acc[i][j] = __builtin_amdgcn_mfma_f32_32x32x16_bf16(aF[i], bF[j], acc[i][j], 0, 0, 0);
    }
    __syncthreads();
  }

  // C/D layout (m74/m101): col = lane&31, row = (reg&3) + 8*(reg>>2) + 4*half
  u16* T = smem;   // [64][136] bounce (aliases staging; loop ended with barrier)

  // row-major epilogue: 4 passes (pr = row half, pc = col half)
#pragma unroll
  for (int pr = 0; pr < 2; pr++)
#pragma unroll
    for (int pc = 0; pc < 2; pc++) {
      if (((wid >> 1) == pr) && ((wid & 1) == pc)) {
#pragma unroll
        for (int i = 0; i < 2; i++)
#pragma unroll
          for (int j = 0; j < 4; j++)
#pragma unroll
            for (int r = 0; r < 16; r++) {
              const int rrow = i * 32 + (r & 3) + 8 * (r >> 2) + 4 * half;  // 0..63
              T[rrow * 136 + j * 32 + l31] = f2bf(acc[i][j][r]);
            }
      }
      __syncthreads();
      {
        const int row = tid >> 2, q = tid & 3;   // 64 rows, 32 u16 each thread
        const size_t crow = (size_t)(m0 + pr * 64 + row) * (N >> 7) + (n0 >> 7) + pc;
        u16* dst = Crow + crow * (size_t)crow_ld + crow_coloff + q * 32;
        const u16* src = T + row * 136 + q * 32;
#pragma unroll
        for (int u = 0; u < 4; u++) ((float4*)dst)[u] = ((const float4*)src)[u];
      }
      __syncthreads();
    }

  if constexpr (MODE == 1) {
    // transposed epilogue: Ct[n][m], 4 passes of 64 n-rows x 128 m-cols
#pragma unroll
    for (int p = 0; p < 4; p++) {
      if ((wid & 1) == (p >> 1)) {            // waves whose wn covers this n-range
        const int jb = (p & 1) * 2;           // j pair {0,1} or {2,3}
#pragma unroll
        for (int i = 0; i < 2; i++)
#pragma unroll
          for (int jj = 0; jj < 2; jj++)
#pragma unroll
            for (int r = 0; r < 16; r++) {
              const int nloc = jj * 32 + l31;                              // 0..63
              const int mcol = wm + i * 32 + (r & 3) + 8 * (r >> 2) + 4 * half;
              T[nloc * 136 + mcol] = f2bf(acc[i][jb + jj][r]);
            }
      }
      __syncthreads();
      {
        const int row = tid >> 2, q = tid & 3;
        u16* dst = Ct + (size_t)(n0 + p * 64 + row) * ct_ld + m0 + q * 32;
        const u16* src = T + row * 136 + q * 32;
#pragma unroll
        for (int u = 0; u < 4; u++) ((float4*)dst)[u] = ((const float4*)src)[u];
      }
      __syncthreads();
    }
  }
}

// ---------------------------------------------------------------------------
// 16x16x32 GEMM (small shapes): MODE 2: bf16 row-major; MODE 3: f32 plain.
// ---------------------------------------------------------------------------
template<int MODE>
__global__ __launch_bounds__(256) void gemm_bt(
    const u16* __restrict__ A, const u16* __restrict__ B,
    int M, int N, int K,
    float* __restrict__ Cf,
    u16* __restrict__ Crow, int crow_ld, int crow_coloff)
{
  extern __shared__ char smemc[];
  u16* sA = (u16*)smemc;
  u16* sB = (u16*)(smemc + 8192);
  const int tid  = threadIdx.x;
  const int lane = tid & 63;
  const int wid  = tid >> 6;
  const int m0 = blockIdx.y * 128;
  const int n0 = blockIdx.x * 128;
  const int wm = (wid >> 1) * 64;
  const int wn = (wid & 1) * 64;
  const int ml = lane & 15;
  const int qd = lane >> 4;

  f32x4 acc[4][4];
  const f32x4 zero = {0.f, 0.f, 0.f, 0.f};
#pragma unroll
  for (int i = 0; i < 4; i++)
#pragma unroll
    for (int j = 0; j < 4; j++) acc[i][j] = zero;

  const int r4 = tid >> 2;
  const int c4 = (tid & 3) * 8;
  const u16* gA0 = A + (size_t)(m0 + r4) * K + c4;
  const u16* gA1 = A + (size_t)(m0 + 64 + r4) * K + c4;
  const u16* gB0 = B + (size_t)(n0 + r4) * K + c4;
  const u16* gB1 = B + (size_t)(n0 + 64 + r4) * K + c4;
  u16* lA0 = sA + wid * 512;
  u16* lA1 = sA + 2048 + wid * 512;
  u16* lB0 = sB + wid * 512;
  u16* lB1 = sB + 2048 + wid * 512;

  for (int k0 = 0; k0 < K; k0 += 32) {
    async_cp16(gA0 + k0, lA0);
    async_cp16(gA1 + k0, lA1);
    async_cp16(gB0 + k0, lB0);
    async_cp16(gB1 + k0, lB1);
    __syncthreads();
    short8 af[4], bfr[4];
#pragma unroll
    for (int i = 0; i < 4; i++)
      af[i] = *(const short8*)(sA + (wm + i * 16 + ml) * 32 + qd * 8);
#pragma unroll
    for (int j = 0; j < 4; j++)
      bfr[j] = *(const short8*)(sB + (wn + j * 16 + ml) * 32 + qd * 8);
#pragma unroll
    for (int i = 0; i < 4; i++)
#pragma unroll
      for (int j = 0; j < 4; j++)
        acc[i][j] = __builtin_amdgcn_mfma_f32_16x16x32_bf16(af[i], bfr[j], acc[i][j], 0, 0, 0);
    __syncthreads();
  }

  if constexpr (MODE == 3) {
#pragma unroll
    for (int i = 0; i < 4; i++) {
      const int mr = m0 + wm + i * 16 + qd * 4;
#pragma unroll
      for (int j = 0; j < 4; j++) {
        const int nc = n0 + wn + j * 16 + ml;
        float* p = Cf + (size_t)mr * N + nc;
#pragma unroll
        for (int r = 0; r < 4; r++) p[(size_t)r * N] = acc[i][j][r];
      }
    }
  } else {
    u16* T = (u16*)smemc;  // [128][136]
#pragma unroll
    for (int i = 0; i < 4; i++)
#pragma unroll
      for (int j = 0; j < 4; j++)
#pragma unroll
        for (int r = 0; r < 4; r++)
          T[(wm + i * 16 + qd * 4 + r) * 136 + wn + j * 16 + ml] = f2bf(acc[i][j][r]);
    __syncthreads();
    const int row = tid >> 1, halfr = tid & 1;
    const size_t crow = (size_t)(m0 + row) * (N >> 7) + (n0 >> 7);
    u16* dst = Crow + crow * (size_t)crow_ld + crow_coloff + halfr * 64;
    const u16* src = T + row * 136 + halfr * 64;
#pragma unroll
    for (int u = 0; u < 8; u++) ((float4*)dst)[u] = ((const float4*)src)[u];
  }
}

// ---------------------------------------------------------------------------
// small kernels
// ---------------------------------------------------------------------------
__global__ void rowsum_k(const float* __restrict__ prior, float* __restrict__ rs) {
  const int i = blockIdx.x, t = threadIdx.x;
  const float* p = prior + (size_t)i * 2048;
  float s = 0.f;
  for (int j = t; j < 2048; j += 256) s += p[j];
  __shared__ float red[256];
  red[t] = s; __syncthreads();
  for (int o = 128; o; o >>= 1) { if (t < o) red[t] += red[t + o]; __syncthreads(); }
  if (t == 0) rs[i] = red[0];
}

__global__ void convprior_k(const float4* __restrict__ prior, const float* __restrict__ rs,
                            ushort4* __restrict__ dst) {
  const int idx = blockIdx.x * 256 + threadIdx.x;
  const float inv = 1.0f / rs[idx >> 9];
  const float4 v = prior[idx];
  ushort4 o;
  o.x = f2bf(v.x * inv); o.y = f2bf(v.y * inv); o.z = f2bf(v.z * inv); o.w = f2bf(v.w * inv);
  dst[idx] = o;
}

__global__ void convx_k(const float* __restrict__ x, u16* __restrict__ xt) {
  __shared__ float S[64][65];
  const int t = threadIdx.x;
  const int j0 = blockIdx.y * 64;
  const int n0 = blockIdx.x * 64;
  const int rr = t >> 4, cxc = (t & 15) * 4;
#pragma unroll
  for (int p = 0; p < 4; p++) {
    const float4 v = *(const float4*)(x + (size_t)(j0 + rr + p * 16) * 8192 + n0 + cxc);
    S[rr + p * 16][cxc + 0] = v.x; S[rr + p * 16][cxc + 1] = v.y;
    S[rr + p * 16][cxc + 2] = v.z; S[rr + p * 16][cxc + 3] = v.w;
  }
  __syncthreads();
  const int nl = t >> 2, ch = (t & 3) * 16;
  alignas(16) u16 tmp[16];
#pragma unroll
  for (int u = 0; u < 16; u++) tmp[u] = f2bf(S[ch + u][nl]);
  float4* dst = (float4*)(xt + (size_t)(n0 + nl) * 2048 + j0 + ch);
  dst[0] = ((const float4*)tmp)[0];
  dst[1] = ((const float4*)tmp)[1];
}

__global__ void convw_k(const float* __restrict__ pw, const float* __restrict__ aw,
                        u16* __restrict__ btc) {
  const int idx = blockIdx.x * 256 + threadIdx.x;
  const int k = idx & 255, d = (idx >> 8) & 127, s = idx >> 15;
  const float v = (k < 128) ? aw[(s * 128 + d) * 128 + k] : pw[(s * 128 + d) * 128 + (k - 128)];
  btc[idx] = f2bf(v);
}

__global__ void pooled1_k(const float* __restrict__ x, float* __restrict__ pooled) {
  const int i = blockIdx.x, t = threadIdx.x;
  const int c = t & 127, h = t >> 7;
  const float* base = x + (size_t)i * 8192 + c;
  float s = 0.f;
  for (int k = h * 32; k < h * 32 + 32; k++) s += base[(size_t)k * 128];
  __shared__ float red[256];
  red[t] = s; __syncthreads();
  if (t < 128) pooled[i * 128 + t] = (red[t] + red[t + 128]) * (1.f / 64.f);
}

__global__ void pooled2_k(const u16* __restrict__ comb, float* __restrict__ pooled) {
  const int i = blockIdx.x, t = threadIdx.x;
  const int c = t & 127, h = t >> 7;
  const u16* base = comb + (size_t)i * 64 * 256 + c;
  float s = 0.f;
  for (int k = h * 32; k < h * 32 + 32; k++) s += bf2f(base[(size_t)k * 256]);
  __shared__ float red[256];
  red[t] = s; __syncthreads();
  if (t < 128) pooled[i * 128 + t] = (red[t] + red[t + 128]) * (1.f / 64.f);
}

__global__ void epre_k(const float* __restrict__ pooled,
                       const float* __restrict__ W1, const float* __restrict__ W2,
                       const float* __restrict__ W3,
                       u16* __restrict__ e3b, u16* __restrict__ fb) {
  const int i = blockIdx.x, d = threadIdx.x;
  __shared__ float pr[128], e1s[64];
  pr[d] = pooled[i * 128 + d];
  pr[d + 64] = pooled[i * 128 + 64 + d];
  __syncthreads();
  float s1 = 0.f, s3 = 0.f;
  for (int c = 0; c < 128; c++) {
    const float p = pr[c];
    s1 += p * W1[d * 128 + c];
    s3 += p * W3[d * 128 + c];
  }
  e1s[d] = s1;
  e3b[i * 64 + d] = f2bf(s3);
  __syncthreads();
  float sf = 0.f;
  for (int dd = 0; dd < 64; dd++) sf += e1s[dd] * W2[d * 64 + dd];
  fb[i * 64 + d] = f2bf(sf);
}

__device__ __forceinline__ float waveRedSum(float v) {
#pragma unroll
  for (int o = 1; o < 64; o <<= 1) v += __shfl_xor(v, o);
  return __shfl(v, 0);
}
__device__ __forceinline__ float waveRedMax(float v) {
#pragma unroll
  for (int o = 1; o < 64; o <<= 1) v = fmaxf(v, __shfl_xor(v, o));
  return __shfl(v, 0);
}

__global__ __launch_bounds__(256) void topp_k(const float* __restrict__ logits,
                                              u16* __restrict__ attnb) {
  const int w = threadIdx.x >> 6, l = threadIdx.x & 63;
  const int i = blockIdx.x * 4 + w;
  const float4* row = (const float4*)(logits + (size_t)i * 2048);
  float E[32];
  float mx = -1e30f;
#pragma unroll
  for (int k = 0; k < 8; k++) {
    const float4 v = row[k * 64 + l];
    E[k * 4 + 0] = v.x; E[k * 4 + 1] = v.y; E[k * 4 + 2] = v.z; E[k * 4 + 3] = v.w;
    mx = fmaxf(fmaxf(mx, fmaxf(v.x, v.y)), fmaxf(v.z, v.w));
  }
  mx = waveRedMax(mx);
  float S = 0.f;
#pragma unroll
  for (int u = 0; u < 32; u++) { E[u] = __expf(E[u] - mx); S += E[u]; }
  S = waveRedSum(S);
  const float target = 0.9f * S;
  float lo = 0.f, hi = 1.f;
  for (int it = 0; it < 32; ++it) {
    const float mid = 0.5f * (lo + hi);
    float g = 0.f;
#pragma unroll
    for (int u = 0; u < 32; u++) g += (E[u] > mid) ? E[u] : 0.f;
    g = waveRedSum(g);
    const bool below = (g < target);
    hi = below ? mid : hi;
    lo = below ? lo : mid;
  }
  float Sk = 0.f;
#pragma unroll
  for (int u = 0; u < 32; u++) Sk += (E[u] > lo) ? E[u] : 0.f;
  Sk = waveRedSum(Sk);
  const float inv = 1.f / Sk;
  u16* dst = attnb + (size_t)i * 2048;
#pragma unroll
  for (int k = 0; k < 8; k++) {
    ushort4 o;
    o.x = f2bf(E[k * 4 + 0] > lo ? E[k * 4 + 0] * inv : 0.f);
    o.y = f2bf(E[k * 4 + 1] > lo ? E[k * 4 + 1] * inv : 0.f);
    o.z = f2bf(E[k * 4 + 2] > lo ? E[k * 4 + 2] * inv : 0.f);
    o.w = f2bf(E[k * 4 + 3] > lo ? E[k * 4 + 3] * inv : 0.f);
    *(ushort4*)(dst + k * 256 + l * 4) = o;
  }
}

// out = LN(x + gate*(d1+d2))*gamma + beta  (deltas stored bf16)
__global__ void ln_k(const float* __restrict__ x,
                     const u16* __restrict__ d1, const u16* __restrict__ d2,
                     float* __restrict__ out,
                     const float* __restrict__ gamma, const float* __restrict__ beta,
                     const float* __restrict__ alpha) {
  const int wid = threadIdx.x >> 6, lane = threadIdx.x & 63;
  const float gate = 1.f / (1.f + expf(-alpha[0]));
  const float2 g = ((const float2*)gamma)[lane];
  const float2 b = ((const float2*)beta)[lane];
#pragma unroll
  for (int rr = 0; rr < 2; ++rr) {
    const size_t row = (size_t)blockIdx.x * 8 + wid * 2 + rr;
    const float2 xv = ((const float2*)(x + row * 128))[lane];
    const ushort2 r1 = ((const ushort2*)(d1 + row * 128))[lane];
    const ushort2 r2 = ((const ushort2*)(d2 + row * 128))[lane];
    const float h0 = xv.x + gate * (bf2f(r1.x) + bf2f(r2.x));
    const float h1 = xv.y + gate * (bf2f(r1.y) + bf2f(r2.y));
    float s = h0 + h1;
#pragma unroll
    for (int o = 32; o; o >>= 1) s += __shfl_down(s, o);
    const float mu = __shfl(s, 0) * (1.f / 128.f);
    const float d0 = h0 - mu, dd1 = h1 - mu;
    float vs = d0 * d0 + dd1 * dd1;
#pragma unroll
    for (int o = 32; o; o >>= 1) vs += __shfl_down(vs, o);
    const float rstd = rsqrtf(__shfl(vs, 0) * (1.f / 128.f) + 1e-5f);
    float2* op = (float2*)(out + row * 128);
    float2 ov;
    ov.x = d0 * rstd * g.x + b.x;
    ov.y = dd1 * rstd * g.y + b.y;
    op[lane] = ov;
  }
}

// ---------------------------------------------------------------------------
extern "C" void kernel_launch(void* const* d_in, const int* in_sizes, int n_in,
                              void* d_out, int out_size, void* d_ws, size_t ws_size,
                              hipStream_t stream) {
  const float* x     = (const float*)d_in[0];
  const float* prior = (const float*)d_in[1];
  const float* W1    = (const float*)d_in[2];
  const float* W2    = (const float*)d_in[3];
  const float* W3    = (const float*)d_in[4];
  const float* Pw    = (const float*)d_in[5];
  const float* Aw    = (const float*)d_in[6];
  const float* gamma = (const float*)d_in[7];
  const float* beta  = (const float*)d_in[8];
  const float* alpha = (const float*)d_in[9];
  float* out = (float*)d_out;

  char* w = (char*)d_ws;
  u16*   Xt_x   = (u16*)(w);                 // 8192x2048 bf16 = 33.55 MB
  u16*   XtA    = (u16*)(w + 33554432);      // 33.55 MB
  u16*   XtF    = (u16*)(w + 67108864);      // 33.55 MB
  u16*   comb   = (u16*)(w + 100663296);     // 131072x256 bf16 [Xa|Xf] = 67.1 MB
  u16*   priorS = (u16*)(w + 167772160);     // 8.39 MB
  u16*   attnb  = (u16*)(w + 176160768);     // 8.39 MB
  float* pooled = (float*)(w + 184549376);   // 1.05 MB
  u16*   e3b    = (u16*)(w + 185597952);     // 256 KB
  u16*   fb     = (u16*)(w + 186122240);     // 256 KB
  float* rs     = (float*)(w + 186646528);   // 8 KB
  u16*   btc    = (u16*)(w + 186654720);     // 2x128x256 bf16 = 131 KB
  // aliased (lifetime-disjoint) regions:
  float* logits1 = (float*)(w + 33554432);   // XtA region: dead until after topp1
  float* logits2 = (float*)(w);              // Xt_x region: dead after MODE-1 GEMMs
  u16*   d1      = (u16*)(w);                // Xt_x region: dead after topp2
  u16*   d2      = (u16*)(w + 33554432);     // XtA region: dead after step-2 Xa GEMM
  (void)in_sizes; (void)n_in; (void)ws_size;

  rowsum_k   <<<2048, 256, 0, stream>>>(prior, rs);
  convprior_k<<<4096, 256, 0, stream>>>((const float4*)prior, rs, (ushort4*)priorS);
  convx_k    <<<dim3(128, 32), 256, 0, stream>>>(x, Xt_x);
  convw_k    <<<256, 256, 0, stream>>>(Pw, Aw, btc);

  // step 1 attention
  pooled1_k  <<<2048, 256, 0, stream>>>(x, pooled);
  epre_k     <<<2048, 64, 0, stream>>>(pooled, W1, W2, W3, e3b, fb);
  gemm_bt<3> <<<dim3(16, 16), 256, 16384, stream>>>(fb, e3b, 2048, 2048, 64,
                                                    logits1, nullptr, 0, 0);
  topp_k     <<<512, 256, 0, stream>>>(logits1, attnb);

  // Xa1 = attn1 @ x ; Xf1 = Rf @ x   (packed [Xa|Xf] bf16 + transposed copies)
  gemm32<1><<<dim3(32, 16), 256, 0, stream>>>(attnb,  Xt_x, 2048, 8192, 2048,
                                              comb, 256, 0,   XtA, 2048);
  gemm32<1><<<dim3(32, 16), 256, 0, stream>>>(priorS, Xt_x, 2048, 8192, 2048,
                                              comb, 256, 128, XtF, 2048);

  // step 2 attention (pooled over Xa1); logits2 aliases the now-dead Xt_x
  pooled2_k  <<<2048, 256, 0, stream>>>(comb, pooled);
  epre_k     <<<2048, 64, 0, stream>>>(pooled, W1, W2, W3, e3b, fb);
  gemm_bt<3> <<<dim3(16, 16), 256, 16384, stream>>>(fb, e3b, 2048, 2048, 64,
                                                    logits2, nullptr, 0, 0);
  topp_k     <<<512, 256, 0, stream>>>(logits2, attnb);

  // d1 = Xa1 @ Aw1^T + Xf1 @ Pw1^T  (bf16, into dead Xt_x region; no RMW)
  gemm_bt<2><<<dim3(1, 1024), 256, 34816, stream>>>(comb, btc, 131072, 128, 256,
                                                    nullptr, d1, 128, 0);

  // Xa2 = attn2 @ Xa1 ; Xf2 = Rf @ Xf1
  gemm32<2><<<dim3(32, 16), 256, 0, stream>>>(attnb,  XtA, 2048, 8192, 2048,
                                              comb, 256, 0,   nullptr, 0);
  gemm32<2><<<dim3(32, 16), 256, 0, stream>>>(priorS, XtF, 2048, 8192, 2048,
                                              comb, 256, 128, nullptr, 0);

  // d2 = Xa2 @ Aw2^T + Xf2 @ Pw2^T  (bf16, into dead XtA region)
  gemm_bt<2><<<dim3(1, 1024), 256, 34816, stream>>>(comb, btc + 32768, 131072, 128, 256,
                                                    nullptr, d2, 128, 0);

  ln_k<<<16384, 256, 0, stream>>>(x, d1, d2, out, gamma, beta, alpha);
}